// Round 1
// baseline (692.411 us; speedup 1.0000x reference)
//
#include <hip/hip_runtime.h>

#define NNODES 8192
#define NEDGES 65536

// ---- folded scale constants ----
// K_P0    = 1/(sqrt32_fc * sqrt64_path)            = 1/sqrt(2048)
// K_P1SS  = 1/(sqrt32_fc * sqrt32 * sqrt2)         = 1/sqrt(2048)
// K_P1SV  = 1/(sqrt32_fc * sqrt32 * sqrt3)         = 1/(32*sqrt3)
// K_P2SS  = 1/(sqrt32_fc * sqrt32 * sqrt2)         = 1/sqrt(2048)
// K_VVS   = 1/(sqrt32_fc * sqrt8  * sqrt2)         = 1/sqrt(512)   (dot carries 1/sqrt3)
// K_VS    = 1/(sqrt32_fc * sqrt8  * sqrt3)         = 1/(16*sqrt3)
// K_VVV   = K_VS / sqrt2                            (crs 1/sqrt2 folded)
#define K_PACK   0.02209708691f
#define K_P1SV   0.01804219593f
#define K_VVS    0.04419417382f
#define K_VS     0.03608439182f
#define K_VVV    0.02551551815f
#define K_DOT    0.57735026919f
#define K_PRELN  0.35355339059f
#define C_EMB    8.4335730689f   // 1.14136 * e^2  (sqrt(10) net-cancels with fcnet /sqrt(10))

__device__ __forceinline__ float siluf(float x) { return x / (1.0f + __expf(-x)); }
__device__ __forceinline__ float susf(float t) { return t > 0.0f ? __expf(-1.0f / t) : 0.0f; }

__device__ __forceinline__ void mlp32(const float* __restrict__ W, const float emb[10],
                                      float* __restrict__ H) {
#pragma unroll
  for (int m = 0; m < 32; ++m) {
    float t = 0.f;
#pragma unroll
    for (int k = 0; k < 10; ++k) t += emb[k] * W[k * 32 + m];
    H[m] = siluf(t);
  }
}

// ---------- prep: node embed (524288) + edge geom/MLPs (65536) + weight packs (139264) ----------
__global__ __launch_bounds__(256) void k_prep(
    const float* __restrict__ pos, const int* __restrict__ z, const int* __restrict__ mol,
    const int* __restrict__ esrc, const int* __restrict__ edst,
    const float* __restrict__ Ez, const float* __restrict__ Em,
    const float* __restrict__ W10, const float* __restrict__ W11, const float* __restrict__ W12,
    const float* __restrict__ W20, const float* __restrict__ W21, const float* __restrict__ W22,
    float* __restrict__ x0, float* __restrict__ sh,
    float* __restrict__ h0, float* __restrict__ h1, float* __restrict__ h2,
    float* __restrict__ Bt0, float* __restrict__ Bt1, float* __restrict__ Bt2) {
  int idx = blockIdx.x * 256 + threadIdx.x;
  if (idx < NNODES * 64) {
    int n = idx >> 6, c = idx & 63;
    x0[idx] = (c < 48) ? Ez[z[n] * 48 + c] : Em[mol[n] * 16 + (c - 48)];
    return;
  }
  idx -= NNODES * 64;
  if (idx < NEDGES) {
    int e = idx;
    int s = esrc[e], d = edst[e];
    float vx = pos[d * 3 + 0] - pos[s * 3 + 0];
    float vy = pos[d * 3 + 1] - pos[s * 3 + 1];
    float vz = pos[d * 3 + 2] - pos[s * 3 + 2];
    float len = sqrtf(vx * vx + vy * vy + vz * vz);
    float inv = 1.7320508076f / fmaxf(len, 1e-9f);  // sqrt(3)/len
    sh[e * 3 + 0] = vx * inv; sh[e * 3 + 1] = vy * inv; sh[e * 3 + 2] = vz * inv;
    float emb[10];
#pragma unroll
    for (int k = 0; k < 10; ++k) {
      float u = len * 1.1f - (float)(k + 1);
      emb[k] = C_EMB * susf(u + 1.0f) * susf(1.0f - u);
    }
    mlp32(W10, emb, h0 + (size_t)e * 32);
    mlp32(W11, emb, h1 + (size_t)e * 32);
    mlp32(W12, emb, h2 + (size_t)e * 32);
    return;
  }
  idx -= NEDGES;
  if (idx < 81920) {  // Bt0[u][c*32+m], u<64, c<40
    int u = idx / 1280; int r = idx - u * 1280; int c = r >> 5; int m = r & 31;
    int col = (c < 32) ? (u * 32 + c) : (2048 + u * 8 + (c - 32));
    Bt0[idx] = W20[m * 2560 + col] * K_PACK;
    return;
  }
  idx -= 81920;
  if (idx < 40960) {  // Bt1[u][c*32+m], u<32, c<40 (32 ss + 8 sv)
    int u = idx / 1280; int r = idx - u * 1280; int c = r >> 5; int m = r & 31;
    float v;
    if (c < 32) v = W21[m * 1664 + u * 32 + c] * K_PACK;
    else        v = W21[m * 1664 + 1280 + u * 8 + (c - 32)] * K_P1SV;
    Bt1[idx] = v;
    return;
  }
  idx -= 40960;
  {  // Bt2[u][c*32+m], u<32, c<16
    int u = idx >> 9; int r = idx & 511; int c = r >> 5; int m = r & 31;
    Bt2[idx] = W22[m * 640 + u * 16 + c] * K_PACK;
  }
}

// ---------- P[n][c][m] = sum_u A[n][u] * Bt[u][c*32+m] ; simple LDS-tiled fp32 GEMM ----------
__global__ __launch_bounds__(256) void k_gemm(
    const float* __restrict__ A, const float* __restrict__ B, float* __restrict__ C,
    int N, int K, int kshift, int lda) {
  __shared__ float As[64][65];
  __shared__ float Bs[64][65];
  int m0 = blockIdx.x * 64, n0 = blockIdx.y * 64;
  int tid = threadIdx.x;
  int tot = K << 6;
  for (int idx = tid; idx < tot; idx += 256) {
    int r = idx >> kshift, k = idx & (K - 1);
    As[r][k] = A[(size_t)(m0 + r) * lda + k];
  }
  for (int idx = tid; idx < tot; idx += 256) {
    int k = idx >> 6, c = idx & 63;
    Bs[k][c] = B[(size_t)k * N + n0 + c];
  }
  __syncthreads();
  int tx = tid & 15, ty = tid >> 4;
  float acc[4][4] = {};
  for (int k = 0; k < K; ++k) {
    float a[4], bb[4];
#pragma unroll
    for (int i = 0; i < 4; ++i) a[i] = As[ty * 4 + i][k];
#pragma unroll
    for (int j = 0; j < 4; ++j) bb[j] = Bs[k][tx * 4 + j];
#pragma unroll
    for (int i = 0; i < 4; ++i)
#pragma unroll
      for (int j = 0; j < 4; ++j) acc[i][j] += a[i] * bb[j];
  }
#pragma unroll
  for (int i = 0; i < 4; ++i) {
    float4 o = make_float4(acc[i][0], acc[i][1], acc[i][2], acc[i][3]);
    *(float4*)&C[(size_t)(m0 + ty * 4 + i) * N + n0 + tx * 4] = o;
  }
}

// ---------- block 0 edge pass: one wave per edge; lanes 0..55 = msg channels ----------
__global__ __launch_bounds__(256) void k_edge0(
    const int* __restrict__ esrc, const int* __restrict__ edst, const float* __restrict__ sh,
    const float* __restrict__ h, const float* __restrict__ P, float* __restrict__ acc) {
  int e = __builtin_amdgcn_readfirstlane(blockIdx.x * 4 + (threadIdx.x >> 6));
  int lane = threadIdx.x & 63;
  int s = esrc[e], d = edst[e];
  float sh0 = sh[e * 3 + 0], sh1 = sh[e * 3 + 1], sh2 = sh[e * 3 + 2];
  int c; float mult;
  if (lane < 32) { c = lane; mult = 1.0f; }
  else if (lane < 56) {
    int l = lane - 32; int v = l / 3; int i = l - v * 3;
    c = 32 + v;
    mult = (i == 0) ? sh0 : (i == 1 ? sh1 : sh2);
  } else { c = 0; mult = 0.0f; }
  const float* hp = h + (size_t)e * 32;
  const float4* Pp = (const float4*)(P + (size_t)s * 1280 + c * 32);
  float a = 0.f;
#pragma unroll
  for (int m4 = 0; m4 < 8; ++m4) {
    float4 p = Pp[m4];
    a += hp[4 * m4 + 0] * p.x + hp[4 * m4 + 1] * p.y + hp[4 * m4 + 2] * p.z + hp[4 * m4 + 3] * p.w;
  }
  if (lane < 56) atomicAdd(&acc[(size_t)d * 56 + lane], a * mult);
}

// ---------- block 1 edge pass ----------
__global__ __launch_bounds__(256) void k_edge1(
    const int* __restrict__ esrc, const int* __restrict__ edst, const float* __restrict__ sh,
    const float* __restrict__ h, const float* __restrict__ P, const float* __restrict__ x1,
    const float* __restrict__ W2, float* __restrict__ acc) {
  int e = __builtin_amdgcn_readfirstlane(blockIdx.x * 4 + (threadIdx.x >> 6));
  int lane = threadIdx.x & 63;
  int s = esrc[e], d = edst[e];
  float sh0 = sh[e * 3 + 0], sh1 = sh[e * 3 + 1], sh2 = sh[e * 3 + 2];
  const float* hp = h + (size_t)e * 32;
  const float* xvp = x1 + (size_t)s * 56 + 32;
  float out = 0.f;
  if (lane < 32) {
    int w = lane;
    const float4* Pp = (const float4*)(P + (size_t)s * 1280 + w * 32);
    float s1 = 0.f;
#pragma unroll
    for (int m4 = 0; m4 < 8; ++m4) {
      float4 p = Pp[m4];
      s1 += hp[4 * m4 + 0] * p.x + hp[4 * m4 + 1] * p.y + hp[4 * m4 + 2] * p.z + hp[4 * m4 + 3] * p.w;
    }
    float du[8];
#pragma unroll
    for (int u = 0; u < 8; ++u)
      du[u] = K_DOT * (xvp[u * 3 + 0] * sh0 + xvp[u * 3 + 1] * sh1 + xvp[u * 3 + 2] * sh2);
    float s2 = 0.f;
    const float* Wb = W2 + 1024 + w;
#pragma unroll 4
    for (int m = 0; m < 32; ++m) {
      const float* Wm = Wb + m * 1664;
      float t = 0.f;
#pragma unroll
      for (int u = 0; u < 8; ++u) t += du[u] * Wm[u * 32];
      s2 += hp[m] * t;
    }
    out = s1 + K_VVS * s2;
  } else if (lane < 56) {
    int l = lane - 32; int v = l / 3; int i = l - v * 3;
    int jj = (i == 2) ? 0 : i + 1;
    int kk = (i == 0) ? 2 : i - 1;
    float shi = (i == 0) ? sh0 : (i == 1 ? sh1 : sh2);
    float shj = (jj == 0) ? sh0 : (jj == 1 ? sh1 : sh2);
    float shk = (kk == 0) ? sh0 : (kk == 1 ? sh1 : sh2);
    float xl[8], cr[8];
#pragma unroll
    for (int u = 0; u < 8; ++u) {
      float xj = xvp[u * 3 + jj], xk = xvp[u * 3 + kk];
      xl[u] = xvp[u * 3 + i];
      cr[u] = xj * shk - xk * shj;  // (xv x sh)_i, 1/sqrt2 folded into K_VVV
    }
    const float4* Pp = (const float4*)(P + (size_t)s * 1280 + (32 + v) * 32);
    float t1 = 0.f;
#pragma unroll
    for (int m4 = 0; m4 < 8; ++m4) {
      float4 p = Pp[m4];
      t1 += hp[4 * m4 + 0] * p.x + hp[4 * m4 + 1] * p.y + hp[4 * m4 + 2] * p.z + hp[4 * m4 + 3] * p.w;
    }
    float t2 = 0.f, t3 = 0.f;
    const float* Wv = W2 + 1536 + v;
    const float* Wc = W2 + 1600 + v;
#pragma unroll 4
    for (int m = 0; m < 32; ++m) {
      const float* a = Wv + m * 1664;
      const float* b = Wc + m * 1664;
      float ta = 0.f, tb = 0.f;
#pragma unroll
      for (int u = 0; u < 8; ++u) { ta += xl[u] * a[u * 8]; tb += cr[u] * b[u * 8]; }
      t2 += hp[m] * ta; t3 += hp[m] * tb;
    }
    out = t1 * shi + K_VS * t2 + K_VVV * t3;
  }
  if (lane < 56) atomicAdd(&acc[(size_t)d * 56 + lane], out);
}

// ---------- block 2 edge pass: 4 edges per wave, 16 lanes each ----------
__global__ __launch_bounds__(256) void k_edge2(
    const int* __restrict__ esrc, const int* __restrict__ edst, const float* __restrict__ sh,
    const float* __restrict__ h, const float* __restrict__ P, const float* __restrict__ x2,
    const float* __restrict__ W2, float* __restrict__ acc) {
  int wid = __builtin_amdgcn_readfirstlane(blockIdx.x * 4 + (threadIdx.x >> 6));
  int lane = threadIdx.x & 63;
  int q = lane >> 4, w = lane & 15;
  int e = wid * 4 + q;
  int s = esrc[e], d = edst[e];
  float sh0 = sh[e * 3 + 0], sh1 = sh[e * 3 + 1], sh2 = sh[e * 3 + 2];
  const float* hp = h + (size_t)e * 32;
  const float* xvp = x2 + (size_t)s * 56 + 32;
  float du[8];
#pragma unroll
  for (int u = 0; u < 8; ++u)
    du[u] = K_DOT * (xvp[u * 3 + 0] * sh0 + xvp[u * 3 + 1] * sh1 + xvp[u * 3 + 2] * sh2);
  const float4* Pp = (const float4*)(P + (size_t)s * 512 + w * 32);
  float s1 = 0.f;
#pragma unroll
  for (int m4 = 0; m4 < 8; ++m4) {
    float4 p = Pp[m4];
    s1 += hp[4 * m4 + 0] * p.x + hp[4 * m4 + 1] * p.y + hp[4 * m4 + 2] * p.z + hp[4 * m4 + 3] * p.w;
  }
  float s2 = 0.f;
  const float* Wb = W2 + 512 + w;
#pragma unroll 4
  for (int m = 0; m < 32; ++m) {
    const float* Wm = Wb + m * 640;
    float t = 0.f;
#pragma unroll
    for (int u = 0; u < 8; ++u) t += du[u] * Wm[u * 16];
    s2 += hp[m] * t;
  }
  atomicAdd(&acc[(size_t)d * 16 + w], s1 + K_VVS * s2);
}

// ---------- LayerNorm: one wave per node ----------
__global__ __launch_bounds__(256) void k_ln(
    const float* __restrict__ acc, const float* __restrict__ g, const float* __restrict__ b,
    float* __restrict__ out, int D, int ostride) {
  int n = __builtin_amdgcn_readfirstlane(blockIdx.x * 4 + (threadIdx.x >> 6));
  int lane = threadIdx.x & 63;
  float v = (lane < D) ? acc[(size_t)n * D + lane] * K_PRELN : 0.f;
  float sm = v, sq = v * v;
#pragma unroll
  for (int off = 32; off > 0; off >>= 1) {
    sm += __shfl_xor(sm, off, 64);
    sq += __shfl_xor(sq, off, 64);
  }
  float invD = 1.0f / (float)D;
  float mean = sm * invD;
  float var = sq * invD - mean * mean;
  float rs = rsqrtf(var + 1e-5f);
  if (lane < D) out[(size_t)n * ostride + lane] = (v - mean) * rs * g[lane] + b[lane];
}

extern "C" void kernel_launch(void* const* d_in, const int* in_sizes, int n_in,
                              void* d_out, int out_size, void* d_ws, size_t ws_size,
                              hipStream_t stream) {
  const float* pos = (const float*)d_in[0];
  const int* z = (const int*)d_in[1];
  const int* mol = (const int*)d_in[2];
  const int* esrc = (const int*)d_in[3];
  const int* edst = (const int*)d_in[4];
  const float* Ez = (const float*)d_in[5];
  const float* Em = (const float*)d_in[6];
  const float* b0W1 = (const float*)d_in[7];
  const float* b0W2 = (const float*)d_in[8];
  const float* b0g = (const float*)d_in[9];
  const float* b0b = (const float*)d_in[10];
  const float* b1W1 = (const float*)d_in[11];
  const float* b1W2 = (const float*)d_in[12];
  const float* b1g = (const float*)d_in[13];
  const float* b1b = (const float*)d_in[14];
  const float* b2W1 = (const float*)d_in[15];
  const float* b2W2 = (const float*)d_in[16];
  const float* b2g = (const float*)d_in[17];
  const float* b2b = (const float*)d_in[18];
  float* out = (float*)d_out;

  float* ws = (float*)d_ws;
  size_t o = 0;
  float* x0 = ws + o;  o += (size_t)NNODES * 64;
  float* x1 = ws + o;  o += (size_t)NNODES * 56;
  float* x2 = ws + o;  o += (size_t)NNODES * 56;
  float* h0 = ws + o;  o += (size_t)NEDGES * 32;
  float* h1 = ws + o;  o += (size_t)NEDGES * 32;
  float* h2 = ws + o;  o += (size_t)NEDGES * 32;
  float* shb = ws + o; o += (size_t)NEDGES * 3;
  float* Bt0 = ws + o; o += 64 * 1280;
  float* Bt1 = ws + o; o += 32 * 1280;
  float* Bt2 = ws + o; o += 32 * 512;
  float* P = ws + o;   o += (size_t)NNODES * 1280;  // reused for P0 / P1 / P2
  float* acc = ws + o; o += (size_t)NNODES * 56;    // reused acc0 / acc1
  float* acc2 = ws + o; o += (size_t)NNODES * 16;   // contiguous after acc

  // zero both accumulators (acc + acc2 contiguous)
  hipMemsetAsync(acc, 0, (size_t)(NNODES * 56 + NNODES * 16) * sizeof(float), stream);

  k_prep<<<2848, 256, 0, stream>>>(pos, z, mol, esrc, edst, Ez, Em,
                                   b0W1, b1W1, b2W1, b0W2, b1W2, b2W2,
                                   x0, shb, h0, h1, h2, Bt0, Bt1, Bt2);

  // block 0
  k_gemm<<<dim3(128, 20), 256, 0, stream>>>(x0, Bt0, P, 1280, 64, 6, 64);
  k_edge0<<<16384, 256, 0, stream>>>(esrc, edst, shb, h0, P, acc);
  k_ln<<<2048, 256, 0, stream>>>(acc, b0g, b0b, x1, 56, 56);

  // block 1
  hipMemsetAsync(acc, 0, (size_t)NNODES * 56 * sizeof(float), stream);
  k_gemm<<<dim3(128, 20), 256, 0, stream>>>(x1, Bt1, P, 1280, 32, 5, 56);
  k_edge1<<<16384, 256, 0, stream>>>(esrc, edst, shb, h1, P, x1, b1W2, acc);
  k_ln<<<2048, 256, 0, stream>>>(acc, b1g, b1b, x2, 56, 56);

  // block 2
  k_gemm<<<dim3(128, 8), 256, 0, stream>>>(x2, Bt2, P, 512, 32, 5, 56);
  k_edge2<<<4096, 256, 0, stream>>>(esrc, edst, shb, h2, P, x2, b2W2, acc2);
  k_ln<<<2048, 256, 0, stream>>>(acc2, b2g, b2b, out, 16, 16);
}

// Round 2
// 317.670 us; speedup vs baseline: 2.1797x; 2.1797x over previous
//
#include <hip/hip_runtime.h>

#define NNODES 8192
#define NEDGES 65536

#define K_PACK   0.02209708691f   // 1/sqrt(2048)
#define K_P1SV   0.01804219593f   // 1/(32*sqrt3)
#define K_VVS    0.04419417382f   // 1/sqrt(512)
#define K_VS     0.03608439182f   // 1/(16*sqrt3)
#define K_VVV    0.02551551815f   // K_VS/sqrt2
#define K_DOT    0.57735026919f
#define K_PRELN  0.35355339059f
#define C_EMB    8.4335730689f

typedef unsigned int uint32;
typedef unsigned short ushort16;

__device__ __forceinline__ float siluf(float x) { return x / (1.0f + __expf(-x)); }
__device__ __forceinline__ float susf(float t) { return t > 0.0f ? __expf(-1.0f / t) : 0.0f; }
__device__ __forceinline__ ushort16 f2bf(float f) {
  uint32 u = __float_as_uint(f);
  return (ushort16)((u + 0x7fffu + ((u >> 16) & 1u)) >> 16);
}
__device__ __forceinline__ float bflo(uint32 v) { return __uint_as_float(v << 16); }
__device__ __forceinline__ float bfhi(uint32 v) { return __uint_as_float(v & 0xffff0000u); }

__device__ __forceinline__ void mlp32(const float* __restrict__ W, const float emb[10],
                                      float* __restrict__ H) {
#pragma unroll
  for (int m = 0; m < 32; ++m) {
    float t = 0.f;
#pragma unroll
    for (int k = 0; k < 10; ++k) t += emb[k] * W[k * 32 + m];
    H[m] = siluf(t);
  }
}

// ---------- prep: edge geom/MLPs, combo ids, X0c, weight packs ----------
__global__ __launch_bounds__(256) void k_prep(
    const float* __restrict__ pos, const int* __restrict__ z, const int* __restrict__ mol,
    const int* __restrict__ esrc, const int* __restrict__ edst,
    const float* __restrict__ Ez, const float* __restrict__ Em,
    const float* __restrict__ W10, const float* __restrict__ W11, const float* __restrict__ W12,
    const float* __restrict__ W20, const float* __restrict__ W21, const float* __restrict__ W22,
    int* __restrict__ combo, float* __restrict__ X0c, float* __restrict__ sh,
    float* __restrict__ h0, float* __restrict__ h1, float* __restrict__ h2,
    float* __restrict__ Bt0, float* __restrict__ Bt1, float* __restrict__ Bt2,
    float* __restrict__ Wp_vvs1, float* __restrict__ Wp_vsv1, float* __restrict__ Wp2) {
  int idx = blockIdx.x * 256 + threadIdx.x;
  if (idx < NEDGES) {
    int e = idx;
    int s = esrc[e], d = edst[e];
    float vx = pos[d * 3 + 0] - pos[s * 3 + 0];
    float vy = pos[d * 3 + 1] - pos[s * 3 + 1];
    float vz = pos[d * 3 + 2] - pos[s * 3 + 2];
    float len = sqrtf(vx * vx + vy * vy + vz * vz);
    float inv = 1.7320508076f / fmaxf(len, 1e-9f);
    sh[e * 3 + 0] = vx * inv; sh[e * 3 + 1] = vy * inv; sh[e * 3 + 2] = vz * inv;
    float emb[10];
#pragma unroll
    for (int k = 0; k < 10; ++k) {
      float u = len * 1.1f - (float)(k + 1);
      emb[k] = C_EMB * susf(u + 1.0f) * susf(1.0f - u);
    }
    mlp32(W10, emb, h0 + (size_t)e * 32);
    mlp32(W11, emb, h1 + (size_t)e * 32);
    mlp32(W12, emb, h2 + (size_t)e * 32);
    return;
  }
  idx -= NEDGES;
  if (idx < NNODES) { combo[idx] = z[idx] * 2 + mol[idx]; return; }
  idx -= NNODES;
  if (idx < 16384) {  // X0c[256][64]
    int c = idx >> 6, j = idx & 63;
    float v = 0.f;
    if (c < 200) {
      int zz = c >> 1, mm = c & 1;
      v = (j < 48) ? Ez[zz * 48 + j] : Em[mm * 16 + (j - 48)];
    }
    X0c[idx] = v;
    return;
  }
  idx -= 16384;
  if (idx < 81920) {  // Bt0[u][c*32+m]
    int u = idx / 1280; int r = idx - u * 1280; int c = r >> 5; int m = r & 31;
    int col = (c < 32) ? (u * 32 + c) : (2048 + u * 8 + (c - 32));
    Bt0[idx] = W20[m * 2560 + col] * K_PACK;
    return;
  }
  idx -= 81920;
  if (idx < 40960) {  // Bt1[u][c*32+m]
    int u = idx / 1280; int r = idx - u * 1280; int c = r >> 5; int m = r & 31;
    Bt1[idx] = (c < 32) ? W21[m * 1664 + u * 32 + c] * K_PACK
                        : W21[m * 1664 + 1280 + u * 8 + (c - 32)] * K_P1SV;
    return;
  }
  idx -= 40960;
  if (idx < 16384) {  // Bt2[u][c*32+m]
    int u = idx >> 9; int r = idx & 511; int c = r >> 5; int m = r & 31;
    Bt2[idx] = W22[m * 640 + u * 16 + c] * K_PACK;
    return;
  }
  idx -= 16384;
  if (idx < 8192) {  // Wp_vvs1[(m*64+lane)*4+j], lane=u*8+wq
    int j = idx & 3, lane = (idx >> 2) & 63, m = idx >> 8;
    int u = lane >> 3, wq = lane & 7;
    Wp_vvs1[idx] = W21[m * 1664 + 1024 + u * 32 + wq * 4 + j] * K_VVS;
    return;
  }
  idx -= 8192;
  if (idx < 4096) {  // Wp_vsv1[(m*64+lane)*2+t], lane=u*8+v
    int t = idx & 1, lane = (idx >> 1) & 63, m = idx >> 7;
    int u = lane >> 3, v = lane & 7;
    Wp_vsv1[idx] = t == 0 ? W21[m * 1664 + 1536 + u * 8 + v] * K_VS
                          : W21[m * 1664 + 1600 + u * 8 + v] * K_VVV;
    return;
  }
  idx -= 4096;
  {  // Wp2[(m*64+lane)*2+t], lane=u*8+wh
    int t = idx & 1, lane = (idx >> 1) & 63, m = idx >> 7;
    int u = lane >> 3, wh = lane & 7;
    Wp2[idx] = W22[m * 640 + 512 + u * 16 + wh * 2 + t] * K_VVS;
  }
}

// ---------- C[M,N] = A[M,K] @ B[K,N], bf16 output ----------
__global__ __launch_bounds__(256) void k_gemm(
    const float* __restrict__ A, const float* __restrict__ B, ushort16* __restrict__ C,
    int N, int K, int kshift, int lda) {
  __shared__ float As[64][65];
  __shared__ float Bs[64][65];
  int m0 = blockIdx.x * 64, n0 = blockIdx.y * 64;
  int tid = threadIdx.x;
  int tot = K << 6;
  for (int idx = tid; idx < tot; idx += 256) {
    int r = idx >> kshift, k = idx & (K - 1);
    As[r][k] = A[(size_t)(m0 + r) * lda + k];
  }
  for (int idx = tid; idx < tot; idx += 256) {
    int k = idx >> 6, c = idx & 63;
    Bs[k][c] = B[(size_t)k * N + n0 + c];
  }
  __syncthreads();
  int tx = tid & 15, ty = tid >> 4;
  float acc[4][4] = {};
  for (int k = 0; k < K; ++k) {
    float a[4], bb[4];
#pragma unroll
    for (int i = 0; i < 4; ++i) a[i] = As[ty * 4 + i][k];
#pragma unroll
    for (int j = 0; j < 4; ++j) bb[j] = Bs[k][tx * 4 + j];
#pragma unroll
    for (int i = 0; i < 4; ++i)
#pragma unroll
      for (int j = 0; j < 4; ++j) acc[i][j] += a[i] * bb[j];
  }
#pragma unroll
  for (int i = 0; i < 4; ++i) {
    uint32 lo = (uint32)f2bf(acc[i][0]) | ((uint32)f2bf(acc[i][1]) << 16);
    uint32 hi = (uint32)f2bf(acc[i][2]) | ((uint32)f2bf(acc[i][3]) << 16);
    uint2 o = make_uint2(lo, hi);
    *(uint2*)&C[(size_t)(m0 + ty * 4 + i) * N + n0 + tx * 4] = o;
  }
}

// ---------- P-gather edge pass: one edge/wave, 56 channels (bf16 P) ----------
__global__ __launch_bounds__(256) void k_edgeP56(
    const int* __restrict__ rowmap, const int* __restrict__ esrc, const int* __restrict__ edst,
    const float* __restrict__ sh, const float* __restrict__ h,
    const ushort16* __restrict__ Pb, float* __restrict__ acc) {
  int e = __builtin_amdgcn_readfirstlane(blockIdx.x * 4 + (threadIdx.x >> 6));
  int lane = threadIdx.x & 63;
  int s = esrc[e], d = edst[e];
  int row = rowmap ? rowmap[s] : s;
  float sh0 = sh[e * 3 + 0], sh1 = sh[e * 3 + 1], sh2 = sh[e * 3 + 2];
  int c; float mult;
  if (lane < 32) { c = lane; mult = 1.0f; }
  else if (lane < 56) {
    int l = lane - 32; int v = l / 3; int i = l - v * 3;
    c = 32 + v;
    mult = (i == 0) ? sh0 : (i == 1 ? sh1 : sh2);
  } else { c = 0; mult = 0.0f; }
  const float* hp = h + (size_t)e * 32;
  const uint4* Pp = reinterpret_cast<const uint4*>(Pb + (size_t)row * 1280 + c * 32);
  float a = 0.f;
#pragma unroll
  for (int q = 0; q < 4; ++q) {
    uint4 pv = Pp[q];
    const float* hq = hp + q * 8;
    a += bflo(pv.x) * hq[0] + bfhi(pv.x) * hq[1];
    a += bflo(pv.y) * hq[2] + bfhi(pv.y) * hq[3];
    a += bflo(pv.z) * hq[4] + bfhi(pv.z) * hq[5];
    a += bflo(pv.w) * hq[6] + bfhi(pv.w) * hq[7];
  }
  if (lane < 56) atomicAdd(&acc[(size_t)d * 56 + lane], a * mult);
}

// ---------- P-gather edge pass: 4 edges/wave, 16 channels (block 2, bf16 P) ----------
__global__ __launch_bounds__(256) void k_edgeP16(
    const int* __restrict__ esrc, const int* __restrict__ edst,
    const float* __restrict__ h, const ushort16* __restrict__ Pb, float* __restrict__ acc) {
  int wid = __builtin_amdgcn_readfirstlane(blockIdx.x * 4 + (threadIdx.x >> 6));
  int lane = threadIdx.x & 63;
  int q = lane >> 4, w = lane & 15;
  int e = wid * 4 + q;
  int s = esrc[e], d = edst[e];
  const float* hp = h + (size_t)e * 32;
  const uint4* Pp = reinterpret_cast<const uint4*>(Pb + (size_t)s * 512 + w * 32);
  float a = 0.f;
#pragma unroll
  for (int qq = 0; qq < 4; ++qq) {
    uint4 pv = Pp[qq];
    const float* hq = hp + qq * 8;
    a += bflo(pv.x) * hq[0] + bfhi(pv.x) * hq[1];
    a += bflo(pv.y) * hq[2] + bfhi(pv.y) * hq[3];
    a += bflo(pv.z) * hq[4] + bfhi(pv.z) * hq[5];
    a += bflo(pv.w) * hq[6] + bfhi(pv.w) * hq[7];
  }
  atomicAdd(&acc[(size_t)d * 16 + w], a);
}

// ---------- block-1 path kernel: register-resident weights, 1 wave/block ----------
__global__ __launch_bounds__(64, 2) void k_edgeW1(
    const int* __restrict__ esrc, const int* __restrict__ edst, const float* __restrict__ sh,
    const float* __restrict__ h, const float* __restrict__ x1,
    const float* __restrict__ Wp_vvs, const float* __restrict__ Wp_vsv,
    float* __restrict__ acc) {
  int lane = threadIdx.x;
  int u = lane >> 3;
  float4 Wv[32]; float2 Wsv[32];
  const float4* Wvp = (const float4*)Wp_vvs;
  const float2* Wsvp = (const float2*)Wp_vsv;
#pragma unroll
  for (int m = 0; m < 32; ++m) { Wv[m] = Wvp[m * 64 + lane]; Wsv[m] = Wsvp[m * 64 + lane]; }
  for (int e0 = blockIdx.x; e0 < NEDGES; e0 += gridDim.x) {
    int e = __builtin_amdgcn_readfirstlane(e0);
    int s = esrc[e], d = edst[e];
    float sh0 = sh[e * 3 + 0], sh1 = sh[e * 3 + 1], sh2 = sh[e * 3 + 2];
    const float* xvp = x1 + (size_t)s * 56 + 32 + u * 3;
    float xv0 = xvp[0], xv1 = xvp[1], xv2 = xvp[2];
    float du = K_DOT * (xv0 * sh0 + xv1 * sh1 + xv2 * sh2);
    float cr0 = xv1 * sh2 - xv2 * sh1;
    float cr1 = xv2 * sh0 - xv0 * sh2;
    float cr2 = xv0 * sh1 - xv1 * sh0;
    const float* hp = h + (size_t)e * 32;
    float b0 = 0.f, b1 = 0.f, b2 = 0.f, b3 = 0.f, avs = 0.f, avv = 0.f;
#pragma unroll
    for (int m = 0; m < 32; ++m) {
      float hm = hp[m];
      b0 += hm * Wv[m].x; b1 += hm * Wv[m].y; b2 += hm * Wv[m].z; b3 += hm * Wv[m].w;
      avs += hm * Wsv[m].x; avv += hm * Wsv[m].y;
    }
    b0 *= du; b1 *= du; b2 *= du; b3 *= du;
    float e0v = xv0 * avs + cr0 * avv;
    float e1v = xv1 * avs + cr1 * avv;
    float e2v = xv2 * avs + cr2 * avv;
#pragma unroll
    for (int off = 8; off < 64; off <<= 1) {
      b0 += __shfl_xor(b0, off, 64); b1 += __shfl_xor(b1, off, 64);
      b2 += __shfl_xor(b2, off, 64); b3 += __shfl_xor(b3, off, 64);
      e0v += __shfl_xor(e0v, off, 64); e1v += __shfl_xor(e1v, off, 64);
      e2v += __shfl_xor(e2v, off, 64);
    }
    if (lane < 8) {
      float* ap = acc + (size_t)d * 56;
      atomicAdd(ap + lane * 4 + 0, b0);
      atomicAdd(ap + lane * 4 + 1, b1);
      atomicAdd(ap + lane * 4 + 2, b2);
      atomicAdd(ap + lane * 4 + 3, b3);
      atomicAdd(ap + 32 + lane * 3 + 0, e0v);
      atomicAdd(ap + 32 + lane * 3 + 1, e1v);
      atomicAdd(ap + 32 + lane * 3 + 2, e2v);
    }
  }
}

// ---------- block-2 vvs path kernel ----------
__global__ __launch_bounds__(64, 4) void k_edgeW2(
    const int* __restrict__ esrc, const int* __restrict__ edst, const float* __restrict__ sh,
    const float* __restrict__ h, const float* __restrict__ x2,
    const float* __restrict__ Wp2, float* __restrict__ acc) {
  int lane = threadIdx.x;
  int u = lane >> 3;
  float2 Wv[32];
  const float2* Wvp = (const float2*)Wp2;
#pragma unroll
  for (int m = 0; m < 32; ++m) Wv[m] = Wvp[m * 64 + lane];
  for (int e0 = blockIdx.x; e0 < NEDGES; e0 += gridDim.x) {
    int e = __builtin_amdgcn_readfirstlane(e0);
    int s = esrc[e], d = edst[e];
    float sh0 = sh[e * 3 + 0], sh1 = sh[e * 3 + 1], sh2 = sh[e * 3 + 2];
    const float* xvp = x2 + (size_t)s * 56 + 32 + u * 3;
    float du = K_DOT * (xvp[0] * sh0 + xvp[1] * sh1 + xvp[2] * sh2);
    const float* hp = h + (size_t)e * 32;
    float c0 = 0.f, c1 = 0.f;
#pragma unroll
    for (int m = 0; m < 32; ++m) {
      float hm = hp[m];
      c0 += hm * Wv[m].x; c1 += hm * Wv[m].y;
    }
    c0 *= du; c1 *= du;
#pragma unroll
    for (int off = 8; off < 64; off <<= 1) {
      c0 += __shfl_xor(c0, off, 64); c1 += __shfl_xor(c1, off, 64);
    }
    if (lane < 8) {
      atomicAdd(&acc[(size_t)d * 16 + lane * 2 + 0], c0);
      atomicAdd(&acc[(size_t)d * 16 + lane * 2 + 1], c1);
    }
  }
}

// ---------- LayerNorm: one wave per node ----------
__global__ __launch_bounds__(256) void k_ln(
    const float* __restrict__ acc, const float* __restrict__ g, const float* __restrict__ b,
    float* __restrict__ out, int D, int ostride) {
  int n = __builtin_amdgcn_readfirstlane(blockIdx.x * 4 + (threadIdx.x >> 6));
  int lane = threadIdx.x & 63;
  float v = (lane < D) ? acc[(size_t)n * D + lane] * K_PRELN : 0.f;
  float sm = v, sq = v * v;
#pragma unroll
  for (int off = 32; off > 0; off >>= 1) {
    sm += __shfl_xor(sm, off, 64);
    sq += __shfl_xor(sq, off, 64);
  }
  float invD = 1.0f / (float)D;
  float mean = sm * invD;
  float var = sq * invD - mean * mean;
  float rs = rsqrtf(var + 1e-5f);
  if (lane < D) out[(size_t)n * ostride + lane] = (v - mean) * rs * g[lane] + b[lane];
}

extern "C" void kernel_launch(void* const* d_in, const int* in_sizes, int n_in,
                              void* d_out, int out_size, void* d_ws, size_t ws_size,
                              hipStream_t stream) {
  const float* pos = (const float*)d_in[0];
  const int* z = (const int*)d_in[1];
  const int* mol = (const int*)d_in[2];
  const int* esrc = (const int*)d_in[3];
  const int* edst = (const int*)d_in[4];
  const float* Ez = (const float*)d_in[5];
  const float* Em = (const float*)d_in[6];
  const float* b0W1 = (const float*)d_in[7];
  const float* b0W2 = (const float*)d_in[8];
  const float* b0g = (const float*)d_in[9];
  const float* b0b = (const float*)d_in[10];
  const float* b1W1 = (const float*)d_in[11];
  const float* b1W2 = (const float*)d_in[12];
  const float* b1g = (const float*)d_in[13];
  const float* b1b = (const float*)d_in[14];
  const float* b2W1 = (const float*)d_in[15];
  const float* b2W2 = (const float*)d_in[16];
  const float* b2g = (const float*)d_in[17];
  const float* b2b = (const float*)d_in[18];
  float* out = (float*)d_out;

  float* ws = (float*)d_ws;
  size_t o = 0;
  int* combo = (int*)(ws + o); o += NNODES;
  float* X0c = ws + o; o += 16384;
  float* x1 = ws + o; o += (size_t)NNODES * 56;
  float* x2 = ws + o; o += (size_t)NNODES * 56;
  float* h0 = ws + o; o += (size_t)NEDGES * 32;
  float* h1 = ws + o; o += (size_t)NEDGES * 32;
  float* h2 = ws + o; o += (size_t)NEDGES * 32;
  float* shb = ws + o; o += (size_t)NEDGES * 3;
  float* Bt0 = ws + o; o += 81920;
  float* Bt1 = ws + o; o += 40960;
  float* Bt2 = ws + o; o += 16384;
  float* Wp_vvs1 = ws + o; o += 8192;
  float* Wp_vsv1 = ws + o; o += 4096;
  float* Wp2 = ws + o; o += 4096;
  ushort16* P0c = (ushort16*)(ws + o); o += 163840;            // 256x1280 bf16
  ushort16* P12 = (ushort16*)(ws + o); o += (size_t)NNODES * 640;  // 8192x1280 bf16
  float* acc = ws + o; o += (size_t)NNODES * 56;
  float* acc2 = ws + o; o += (size_t)NNODES * 16;

  hipMemsetAsync(acc, 0, (size_t)(NNODES * 56 + NNODES * 16) * sizeof(float), stream);

  k_prep<<<960, 256, 0, stream>>>(pos, z, mol, esrc, edst, Ez, Em,
                                  b0W1, b1W1, b2W1, b0W2, b1W2, b2W2,
                                  combo, X0c, shb, h0, h1, h2, Bt0, Bt1, Bt2,
                                  Wp_vvs1, Wp_vsv1, Wp2);

  // block 0: P0c = X0c @ Bt0 (only 200 distinct rows), then gather by combo[src]
  k_gemm<<<dim3(4, 20), 256, 0, stream>>>(X0c, Bt0, P0c, 1280, 64, 6, 64);
  k_edgeP56<<<16384, 256, 0, stream>>>(combo, esrc, edst, shb, h0, P0c, acc);
  k_ln<<<2048, 256, 0, stream>>>(acc, b0g, b0b, x1, 56, 56);

  // block 1
  hipMemsetAsync(acc, 0, (size_t)NNODES * 56 * sizeof(float), stream);
  k_gemm<<<dim3(128, 20), 256, 0, stream>>>(x1, Bt1, P12, 1280, 32, 5, 56);
  k_edgeP56<<<16384, 256, 0, stream>>>(nullptr, esrc, edst, shb, h1, P12, acc);
  k_edgeW1<<<2048, 64, 0, stream>>>(esrc, edst, shb, h1, x1, Wp_vvs1, Wp_vsv1, acc);
  k_ln<<<2048, 256, 0, stream>>>(acc, b1g, b1b, x2, 56, 56);

  // block 2
  k_gemm<<<dim3(128, 8), 256, 0, stream>>>(x2, Bt2, P12, 512, 32, 5, 56);
  k_edgeP16<<<4096, 256, 0, stream>>>(esrc, edst, h2, P12, acc2);
  k_edgeW2<<<2048, 64, 0, stream>>>(esrc, edst, shb, h2, x2, Wp2, acc2);
  k_ln<<<2048, 256, 0, stream>>>(acc2, b2g, b2b, out, 16, 16);
}

// Round 3
// 290.573 us; speedup vs baseline: 2.3829x; 1.0933x over previous
//
#include <hip/hip_runtime.h>

#define NNODES 8192
#define NEDGES 65536

#define K_PACK   0.02209708691f   // 1/sqrt(2048)
#define K_P1SV   0.01804219593f   // 1/(32*sqrt3)
#define K_VVS    0.04419417382f   // 1/sqrt(512)
#define K_VS     0.03608439182f   // 1/(16*sqrt3)
#define K_VVV    0.02551551815f   // K_VS/sqrt2
#define K_DOT    0.57735026919f
#define K_PRELN  0.35355339059f
#define C_EMB    8.4335730689f

typedef unsigned int uint32;
typedef unsigned short ushort16;
typedef __attribute__((ext_vector_type(8))) short short8;
typedef __attribute__((ext_vector_type(4))) float floatx4;

__device__ __forceinline__ float siluf(float x) { return x / (1.0f + __expf(-x)); }
__device__ __forceinline__ float susf(float t) { return t > 0.0f ? __expf(-1.0f / t) : 0.0f; }
__device__ __forceinline__ ushort16 f2bf(float f) {
  uint32 u = __float_as_uint(f);
  return (ushort16)((u + 0x7fffu + ((u >> 16) & 1u)) >> 16);
}
__device__ __forceinline__ float bflo(uint32 v) { return __uint_as_float(v << 16); }
__device__ __forceinline__ float bfhi(uint32 v) { return __uint_as_float(v & 0xffff0000u); }

__device__ __forceinline__ void mlp32(const float* __restrict__ W, const float emb[10],
                                      float* __restrict__ H) {
#pragma unroll
  for (int m = 0; m < 32; ++m) {
    float t = 0.f;
#pragma unroll
    for (int k = 0; k < 10; ++k) t += emb[k] * W[k * 32 + m];
    H[m] = siluf(t);
  }
}

// ---------- prep: edge geom/MLPs, combo ids, X0cb, MFMA-layout B packs, W packs ----------
__global__ __launch_bounds__(256) void k_prep(
    const float* __restrict__ pos, const int* __restrict__ z, const int* __restrict__ mol,
    const int* __restrict__ esrc, const int* __restrict__ edst,
    const float* __restrict__ Ez, const float* __restrict__ Em,
    const float* __restrict__ W10, const float* __restrict__ W11, const float* __restrict__ W12,
    const float* __restrict__ W20, const float* __restrict__ W21, const float* __restrict__ W22,
    int* __restrict__ combo, ushort16* __restrict__ X0cb, float* __restrict__ sh,
    float* __restrict__ h0, float* __restrict__ h1, float* __restrict__ h2,
    ushort16* __restrict__ Bp0, ushort16* __restrict__ Bp1, ushort16* __restrict__ Bp2,
    float* __restrict__ Wp_vvs1, float* __restrict__ Wp_vsv1, float* __restrict__ Wp2) {
  int idx = blockIdx.x * 256 + threadIdx.x;
  if (idx < NEDGES) {
    int e = idx;
    int s = esrc[e], d = edst[e];
    float vx = pos[d * 3 + 0] - pos[s * 3 + 0];
    float vy = pos[d * 3 + 1] - pos[s * 3 + 1];
    float vz = pos[d * 3 + 2] - pos[s * 3 + 2];
    float len = sqrtf(vx * vx + vy * vy + vz * vz);
    float inv = 1.7320508076f / fmaxf(len, 1e-9f);
    sh[e * 3 + 0] = vx * inv; sh[e * 3 + 1] = vy * inv; sh[e * 3 + 2] = vz * inv;
    float emb[10];
#pragma unroll
    for (int k = 0; k < 10; ++k) {
      float u = len * 1.1f - (float)(k + 1);
      emb[k] = C_EMB * susf(u + 1.0f) * susf(1.0f - u);
    }
    mlp32(W10, emb, h0 + (size_t)e * 32);
    mlp32(W11, emb, h1 + (size_t)e * 32);
    mlp32(W12, emb, h2 + (size_t)e * 32);
    return;
  }
  idx -= NEDGES;
  if (idx < NNODES) { combo[idx] = z[idx] * 2 + mol[idx]; return; }
  idx -= NNODES;
  if (idx < 16384) {  // X0cb[256][64] bf16
    int c = idx >> 6, j = idx & 63;
    float v = 0.f;
    if (c < 200) {
      int zz = c >> 1, mm = c & 1;
      v = (j < 48) ? Ez[zz * 48 + j] : Em[mm * 16 + (j - 48)];
    }
    X0cb[idx] = f2bf(v);
    return;
  }
  idx -= 16384;
  if (idx < 81920) {  // Bp0[tile(80)][kh(2)][lane(64)][j(8)] bf16, K=64
    int tile = idx >> 10; int r = idx & 1023;
    int kh = r >> 9; int rr = r & 511;
    int lane = rr >> 3, j = rr & 7;
    int k = kh * 32 + (lane >> 4) * 8 + j;
    int n = tile * 16 + (lane & 15);
    int c = n >> 5, m = n & 31;
    int col = (c < 32) ? (k * 32 + c) : (2048 + k * 8 + (c - 32));
    Bp0[idx] = f2bf(W20[m * 2560 + col] * K_PACK);
    return;
  }
  idx -= 81920;
  if (idx < 40960) {  // Bp1[tile(80)][lane][j] bf16, K=32
    int tile = idx >> 9; int rr = idx & 511;
    int lane = rr >> 3, j = rr & 7;
    int k = (lane >> 4) * 8 + j;
    int n = tile * 16 + (lane & 15);
    int c = n >> 5, m = n & 31;
    float v = (c < 32) ? W21[m * 1664 + k * 32 + c] * K_PACK
                       : W21[m * 1664 + 1280 + k * 8 + (c - 32)] * K_P1SV;
    Bp1[idx] = f2bf(v);
    return;
  }
  idx -= 40960;
  if (idx < 16384) {  // Bp2[tile(32)][lane][j] bf16, K=32
    int tile = idx >> 9; int rr = idx & 511;
    int lane = rr >> 3, j = rr & 7;
    int k = (lane >> 4) * 8 + j;
    int n = tile * 16 + (lane & 15);
    int c = n >> 5, m = n & 31;
    Bp2[idx] = f2bf(W22[m * 640 + k * 16 + c] * K_PACK);
    return;
  }
  idx -= 16384;
  if (idx < 8192) {  // Wp_vvs1[(m*64+lane)*4+j], lane=u*8+wq
    int j = idx & 3, lane = (idx >> 2) & 63, m = idx >> 8;
    int u = lane >> 3, wq = lane & 7;
    Wp_vvs1[idx] = W21[m * 1664 + 1024 + u * 32 + wq * 4 + j] * K_VVS;
    return;
  }
  idx -= 8192;
  if (idx < 4096) {  // Wp_vsv1[(m*64+lane)*2+t], lane=u*8+v
    int t = idx & 1, lane = (idx >> 1) & 63, m = idx >> 7;
    int u = lane >> 3, v = lane & 7;
    Wp_vsv1[idx] = t == 0 ? W21[m * 1664 + 1536 + u * 8 + v] * K_VS
                          : W21[m * 1664 + 1600 + u * 8 + v] * K_VVV;
    return;
  }
  idx -= 4096;
  {  // Wp2[(m*64+lane)*2+t], lane=u*8+wh
    int t = idx & 1, lane = (idx >> 1) & 63, m = idx >> 7;
    int u = lane >> 3, wh = lane & 7;
    Wp2[idx] = W22[m * 640 + 512 + u * 16 + wh * 2 + t] * K_VVS;
  }
}

// ---------- MFMA GEMM: C[M,N](bf16) = A[M,K](bf16) @ Bp(frag-packed bf16); K in {32,64} ----------
// grid (M/64, N/64), block 256: wave w -> m-tile bx*4+w, n-tiles [by*4 .. by*4+4)
__global__ __launch_bounds__(256) void k_gemm_mfma(
    const ushort16* __restrict__ A, const ushort16* __restrict__ Bp, ushort16* __restrict__ C,
    int N, int K) {
  int wave = threadIdx.x >> 6, lane = threadIdx.x & 63;
  int m0 = blockIdx.x * 64 + wave * 16;
  int n0 = blockIdx.y * 64;
  int row = lane & 15, q = lane >> 4;
  int nkh = K >> 5;
  floatx4 acc[4];
  floatx4 zero = {0.f, 0.f, 0.f, 0.f};
#pragma unroll
  for (int t = 0; t < 4; ++t) acc[t] = zero;
  for (int kh = 0; kh < nkh; ++kh) {
    short8 a = *reinterpret_cast<const short8*>(A + (size_t)(m0 + row) * K + kh * 32 + q * 8);
#pragma unroll
    for (int t = 0; t < 4; ++t) {
      int T = (n0 >> 4) + t;
      short8 b = *reinterpret_cast<const short8*>(Bp + ((size_t)T * nkh + kh) * 512 + lane * 8);
      acc[t] = __builtin_amdgcn_mfma_f32_16x16x32_bf16(a, b, acc[t], 0, 0, 0);
    }
  }
  int colb = n0 + row;
#pragma unroll
  for (int t = 0; t < 4; ++t)
#pragma unroll
    for (int r = 0; r < 4; ++r)
      C[(size_t)(m0 + q * 4 + r) * N + colb + t * 16] = f2bf(acc[t][r]);
}

// ---------- P-gather edge pass: one edge/wave, 56 channels (bf16 P) ----------
__global__ __launch_bounds__(256) void k_edgeP56(
    const int* __restrict__ rowmap, const int* __restrict__ esrc, const int* __restrict__ edst,
    const float* __restrict__ sh, const float* __restrict__ h,
    const ushort16* __restrict__ Pb, float* __restrict__ acc) {
  int e = __builtin_amdgcn_readfirstlane(blockIdx.x * 4 + (threadIdx.x >> 6));
  int lane = threadIdx.x & 63;
  int s = esrc[e], d = edst[e];
  int row = rowmap ? rowmap[s] : s;
  float sh0 = sh[e * 3 + 0], sh1 = sh[e * 3 + 1], sh2 = sh[e * 3 + 2];
  int c; float mult;
  if (lane < 32) { c = lane; mult = 1.0f; }
  else if (lane < 56) {
    int l = lane - 32; int v = l / 3; int i = l - v * 3;
    c = 32 + v;
    mult = (i == 0) ? sh0 : (i == 1 ? sh1 : sh2);
  } else { c = 0; mult = 0.0f; }
  const float* hp = h + (size_t)e * 32;
  const uint4* Pp = reinterpret_cast<const uint4*>(Pb + (size_t)row * 1280 + c * 32);
  float a = 0.f;
#pragma unroll
  for (int qq = 0; qq < 4; ++qq) {
    uint4 pv = Pp[qq];
    const float* hq = hp + qq * 8;
    a += bflo(pv.x) * hq[0] + bfhi(pv.x) * hq[1];
    a += bflo(pv.y) * hq[2] + bfhi(pv.y) * hq[3];
    a += bflo(pv.z) * hq[4] + bfhi(pv.z) * hq[5];
    a += bflo(pv.w) * hq[6] + bfhi(pv.w) * hq[7];
  }
  if (lane < 56) atomicAdd(&acc[(size_t)d * 56 + lane], a * mult);
}

// ---------- P-gather edge pass: 4 edges/wave, 16 channels (block 2, bf16 P) ----------
__global__ __launch_bounds__(256) void k_edgeP16(
    const int* __restrict__ esrc, const int* __restrict__ edst,
    const float* __restrict__ h, const ushort16* __restrict__ Pb, float* __restrict__ acc) {
  int wid = __builtin_amdgcn_readfirstlane(blockIdx.x * 4 + (threadIdx.x >> 6));
  int lane = threadIdx.x & 63;
  int q = lane >> 4, w = lane & 15;
  int e = wid * 4 + q;
  int s = esrc[e], d = edst[e];
  const float* hp = h + (size_t)e * 32;
  const uint4* Pp = reinterpret_cast<const uint4*>(Pb + (size_t)s * 512 + w * 32);
  float a = 0.f;
#pragma unroll
  for (int qq = 0; qq < 4; ++qq) {
    uint4 pv = Pp[qq];
    const float* hq = hp + qq * 8;
    a += bflo(pv.x) * hq[0] + bfhi(pv.x) * hq[1];
    a += bflo(pv.y) * hq[2] + bfhi(pv.y) * hq[3];
    a += bflo(pv.z) * hq[4] + bfhi(pv.z) * hq[5];
    a += bflo(pv.w) * hq[6] + bfhi(pv.w) * hq[7];
  }
  atomicAdd(&acc[(size_t)d * 16 + w], a);
}

// ---------- block-1 path kernel: weights pinned in VGPRs via asm barrier ----------
__global__ __launch_bounds__(64, 2) void k_edgeW1(
    const int* __restrict__ esrc, const int* __restrict__ edst, const float* __restrict__ sh,
    const float* __restrict__ h, const float* __restrict__ xv1,
    const float* __restrict__ Wp_vvs, const float* __restrict__ Wp_vsv,
    float* __restrict__ acc) {
  int lane = threadIdx.x;
  int u = lane >> 3;
  float4 Wv[32]; float2 Wsv[32];
  const float4* Wvp = (const float4*)Wp_vvs;
  const float2* Wsvp = (const float2*)Wp_vsv;
#pragma unroll
  for (int m = 0; m < 32; ++m) { Wv[m] = Wvp[m * 64 + lane]; Wsv[m] = Wsvp[m * 64 + lane]; }
#pragma unroll
  for (int m = 0; m < 32; ++m)
    asm volatile("" : "+v"(Wv[m].x), "+v"(Wv[m].y), "+v"(Wv[m].z), "+v"(Wv[m].w),
                      "+v"(Wsv[m].x), "+v"(Wsv[m].y));
  for (int e0 = blockIdx.x; e0 < NEDGES; e0 += gridDim.x) {
    int e = __builtin_amdgcn_readfirstlane(e0);
    int s = esrc[e], d = edst[e];
    float sh0 = sh[e * 3 + 0], sh1 = sh[e * 3 + 1], sh2 = sh[e * 3 + 2];
    const float* xvp = xv1 + (size_t)s * 24 + u * 3;
    float xv0 = xvp[0], xv1v = xvp[1], xv2v = xvp[2];
    float du = K_DOT * (xv0 * sh0 + xv1v * sh1 + xv2v * sh2);
    float cr0 = xv1v * sh2 - xv2v * sh1;
    float cr1 = xv2v * sh0 - xv0 * sh2;
    float cr2 = xv0 * sh1 - xv1v * sh0;
    const float* hp = h + (size_t)e * 32;
    float b0 = 0.f, b1 = 0.f, b2 = 0.f, b3 = 0.f, avs = 0.f, avv = 0.f;
#pragma unroll
    for (int m = 0; m < 32; ++m) {
      float hm = hp[m];
      b0 += hm * Wv[m].x; b1 += hm * Wv[m].y; b2 += hm * Wv[m].z; b3 += hm * Wv[m].w;
      avs += hm * Wsv[m].x; avv += hm * Wsv[m].y;
    }
    b0 *= du; b1 *= du; b2 *= du; b3 *= du;
    float e0v = xv0 * avs + cr0 * avv;
    float e1v = xv1v * avs + cr1 * avv;
    float e2v = xv2v * avs + cr2 * avv;
#pragma unroll
    for (int off = 8; off < 64; off <<= 1) {
      b0 += __shfl_xor(b0, off, 64); b1 += __shfl_xor(b1, off, 64);
      b2 += __shfl_xor(b2, off, 64); b3 += __shfl_xor(b3, off, 64);
      e0v += __shfl_xor(e0v, off, 64); e1v += __shfl_xor(e1v, off, 64);
      e2v += __shfl_xor(e2v, off, 64);
    }
    if (lane < 8) {
      float* ap = acc + (size_t)d * 56;
      atomicAdd(ap + lane * 4 + 0, b0);
      atomicAdd(ap + lane * 4 + 1, b1);
      atomicAdd(ap + lane * 4 + 2, b2);
      atomicAdd(ap + lane * 4 + 3, b3);
      atomicAdd(ap + 32 + lane * 3 + 0, e0v);
      atomicAdd(ap + 32 + lane * 3 + 1, e1v);
      atomicAdd(ap + 32 + lane * 3 + 2, e2v);
    }
  }
}

// ---------- block-2 vvs path kernel ----------
__global__ __launch_bounds__(64, 4) void k_edgeW2(
    const int* __restrict__ esrc, const int* __restrict__ edst, const float* __restrict__ sh,
    const float* __restrict__ h, const float* __restrict__ xv2,
    const float* __restrict__ Wp2, float* __restrict__ acc) {
  int lane = threadIdx.x;
  int u = lane >> 3;
  float2 Wv[32];
  const float2* Wvp = (const float2*)Wp2;
#pragma unroll
  for (int m = 0; m < 32; ++m) Wv[m] = Wvp[m * 64 + lane];
#pragma unroll
  for (int m = 0; m < 32; ++m)
    asm volatile("" : "+v"(Wv[m].x), "+v"(Wv[m].y));
  for (int e0 = blockIdx.x; e0 < NEDGES; e0 += gridDim.x) {
    int e = __builtin_amdgcn_readfirstlane(e0);
    int s = esrc[e], d = edst[e];
    float sh0 = sh[e * 3 + 0], sh1 = sh[e * 3 + 1], sh2 = sh[e * 3 + 2];
    const float* xvp = xv2 + (size_t)s * 24 + u * 3;
    float du = K_DOT * (xvp[0] * sh0 + xvp[1] * sh1 + xvp[2] * sh2);
    const float* hp = h + (size_t)e * 32;
    float c0 = 0.f, c1 = 0.f;
#pragma unroll
    for (int m = 0; m < 32; ++m) {
      float hm = hp[m];
      c0 += hm * Wv[m].x; c1 += hm * Wv[m].y;
    }
    c0 *= du; c1 *= du;
#pragma unroll
    for (int off = 8; off < 64; off <<= 1) {
      c0 += __shfl_xor(c0, off, 64); c1 += __shfl_xor(c1, off, 64);
    }
    if (lane < 8) {
      atomicAdd(&acc[(size_t)d * 16 + lane * 2 + 0], c0);
      atomicAdd(&acc[(size_t)d * 16 + lane * 2 + 1], c1);
    }
  }
}

// ---------- LayerNorm: one wave per node; optionally zero a buffer for later use ----------
__global__ __launch_bounds__(256) void k_ln(
    const float* __restrict__ acc, const float* __restrict__ g, const float* __restrict__ b,
    ushort16* __restrict__ xsb, float* __restrict__ xvf, float* __restrict__ outf, int D,
    float* __restrict__ zbuf, int zn) {
  if (zbuf) {
    int gt = blockIdx.x * 256 + threadIdx.x;
    int stride = gridDim.x * 256;
    for (int i = gt; i < zn; i += stride) zbuf[i] = 0.f;
  }
  int n = __builtin_amdgcn_readfirstlane(blockIdx.x * 4 + (threadIdx.x >> 6));
  int lane = threadIdx.x & 63;
  float v = (lane < D) ? acc[(size_t)n * D + lane] * K_PRELN : 0.f;
  float sm = v, sq = v * v;
#pragma unroll
  for (int off = 32; off > 0; off >>= 1) {
    sm += __shfl_xor(sm, off, 64);
    sq += __shfl_xor(sq, off, 64);
  }
  float invD = 1.0f / (float)D;
  float mean = sm * invD;
  float var = sq * invD - mean * mean;
  float rs = rsqrtf(var + 1e-5f);
  float r = (v - mean) * rs * g[lane < D ? lane : 0] + b[lane < D ? lane : 0];
  if (outf) {
    if (lane < D) outf[(size_t)n * D + lane] = r;
  } else {
    if (lane < 32) xsb[(size_t)n * 32 + lane] = f2bf(r);
    else if (lane < 56) xvf[(size_t)n * 24 + lane - 32] = r;
  }
}

extern "C" void kernel_launch(void* const* d_in, const int* in_sizes, int n_in,
                              void* d_out, int out_size, void* d_ws, size_t ws_size,
                              hipStream_t stream) {
  const float* pos = (const float*)d_in[0];
  const int* z = (const int*)d_in[1];
  const int* mol = (const int*)d_in[2];
  const int* esrc = (const int*)d_in[3];
  const int* edst = (const int*)d_in[4];
  const float* Ez = (const float*)d_in[5];
  const float* Em = (const float*)d_in[6];
  const float* b0W1 = (const float*)d_in[7];
  const float* b0W2 = (const float*)d_in[8];
  const float* b0g = (const float*)d_in[9];
  const float* b0b = (const float*)d_in[10];
  const float* b1W1 = (const float*)d_in[11];
  const float* b1W2 = (const float*)d_in[12];
  const float* b1g = (const float*)d_in[13];
  const float* b1b = (const float*)d_in[14];
  const float* b2W1 = (const float*)d_in[15];
  const float* b2W2 = (const float*)d_in[16];
  const float* b2g = (const float*)d_in[17];
  const float* b2b = (const float*)d_in[18];
  float* out = (float*)d_out;

  float* ws = (float*)d_ws;
  size_t o = 0;
  int* combo = (int*)(ws + o); o += NNODES;
  ushort16* X0cb = (ushort16*)(ws + o); o += 8192;       // 256x64 bf16
  ushort16* xs1b = (ushort16*)(ws + o); o += 131072;     // 8192x32 bf16
  float* xv1 = ws + o; o += (size_t)NNODES * 24;         // 8192x24 f32
  float* h0 = ws + o; o += (size_t)NEDGES * 32;          // acc1 aliases h0 (dead after edgeP56 b0)
  float* h1 = ws + o; o += (size_t)NEDGES * 32;
  float* h2 = ws + o; o += (size_t)NEDGES * 32;
  float* shb = ws + o; o += (size_t)NEDGES * 3;
  ushort16* Bp0 = (ushort16*)(ws + o); o += 40960;       // 80x2x512 bf16
  ushort16* Bp1 = (ushort16*)(ws + o); o += 20480;       // 80x512 bf16
  ushort16* Bp2 = (ushort16*)(ws + o); o += 8192;        // 32x512 bf16
  float* Wp_vvs1 = ws + o; o += 8192;
  float* Wp_vsv1 = ws + o; o += 4096;
  float* Wp2 = ws + o; o += 4096;
  ushort16* P12 = (ushort16*)(ws + o); o += (size_t)NNODES * 640;  // 8192x1280 bf16
  float* acc0 = ws + o; o += (size_t)NNODES * 56;
  float* acc2 = ws + o; o += (size_t)NNODES * 16;        // contiguous after acc0

  ushort16* P0c = P12;          // 256x1280 bf16, consumed before gemm1 overwrites
  float* acc1 = h0;             // zeroed by ln0 (h0 dead by then)
  ushort16* xs2b = xs1b;        // xs1b dead after gemm1
  float* xv2 = xv1;             // xv1 dead after edgeW1

  hipMemsetAsync(acc0, 0, (size_t)(NNODES * 56 + NNODES * 16) * sizeof(float), stream);

  k_prep<<<960, 256, 0, stream>>>(pos, z, mol, esrc, edst, Ez, Em,
                                  b0W1, b1W1, b2W1, b0W2, b1W2, b2W2,
                                  combo, X0cb, shb, h0, h1, h2, Bp0, Bp1, Bp2,
                                  Wp_vvs1, Wp_vsv1, Wp2);

  // block 0: P0c = X0cb @ Bp0 (200 distinct rows), gather by combo[src]
  k_gemm_mfma<<<dim3(4, 20), 256, 0, stream>>>(X0cb, Bp0, P0c, 1280, 64);
  k_edgeP56<<<16384, 256, 0, stream>>>(combo, esrc, edst, shb, h0, P0c, acc0);
  k_ln<<<2048, 256, 0, stream>>>(acc0, b0g, b0b, xs1b, xv1, nullptr, 56, acc1, NNODES * 56);

  // block 1
  k_gemm_mfma<<<dim3(128, 20), 256, 0, stream>>>(xs1b, Bp1, P12, 1280, 32);
  k_edgeP56<<<16384, 256, 0, stream>>>(nullptr, esrc, edst, shb, h1, P12, acc1);
  k_edgeW1<<<2048, 64, 0, stream>>>(esrc, edst, shb, h1, xv1, Wp_vvs1, Wp_vsv1, acc1);
  k_ln<<<2048, 256, 0, stream>>>(acc1, b1g, b1b, xs2b, xv2, nullptr, 56, nullptr, 0);

  // block 2
  k_gemm_mfma<<<dim3(128, 8), 256, 0, stream>>>(xs2b, Bp2, P12, 512, 32);
  k_edgeP16<<<4096, 256, 0, stream>>>(esrc, edst, h2, P12, acc2);
  k_edgeW2<<<4096, 64, 0, stream>>>(esrc, edst, shb, h2, xv2, Wp2, acc2);
  k_ln<<<2048, 256, 0, stream>>>(acc2, b2g, b2b, nullptr, nullptr, out, 16, nullptr, 0);
}